// Round 15
// baseline (75.063 us; speedup 1.0000x reference)
//
#include <hip/hip_runtime.h>
#include <hip/hip_bf16.h>

typedef _Float16 half_t;
typedef _Float16 f16x8 __attribute__((ext_vector_type(8)));
typedef _Float16 f16x4 __attribute__((ext_vector_type(4)));
typedef float f32x4 __attribute__((ext_vector_type(4)));

#define LEAKY 0.1f

// ===========================================================================
// prep (all weight transforms):
//  wp1  = [co(48)][40]              k = tap*3+ci, 27..39 = 0   (1920)
//  wp2  = [tap10][ci8(6)][m16][nt3][j8] packed B for conv2     (23040)
//  wp3s = [co(48)][kc(56)][j(8)]    swapped-A for conv3        (21504)
//  wp4  = same packed-B layout as wp2, from w4                 (23040)
// ===========================================================================
__global__ __launch_bounds__(512) void prep_w_k(const float* __restrict__ w1,
                                                const float* __restrict__ w2,
                                                const float* __restrict__ w3,
                                                const float* __restrict__ w4,
                                                half_t* __restrict__ wp1,
                                                half_t* __restrict__ wp2,
                                                half_t* __restrict__ wp3s,
                                                half_t* __restrict__ wp4)
{
    int t = blockIdx.x * 512 + threadIdx.x;
    if (t < 1920) {
        int co = t / 40, kk = t % 40;
        float v = 0.f;
        if (kk < 27) {
            int tap = kk / 3, ci = kk % 3;
            v = w1[((co * 3 + ci) * 3 + tap / 3) * 3 + tap % 3];
        }
        wp1[t] = (half_t)v;
        return;
    }
    t -= 1920;
    if (t < 23040) {
        int tap = t / 2304, r = t % 2304;
        int ci8 = r / 384, r2 = r % 384;
        int mm = r2 / 24, r3 = r2 % 24;
        int nt = r3 / 8, j = r3 % 8;
        int co = nt * 16 + mm, ci = ci8 * 8 + j;
        float v = 0.f;
        if (tap < 9) v = w2[((co * 48 + ci) * 3 + tap / 3) * 3 + tap % 3];
        wp2[t] = (half_t)v;
        return;
    }
    t -= 23040;
    if (t < 21504) {
        int co = t / 448, r = t % 448;
        int kc = r / 8, j = r % 8;
        int tap = kc / 6, ci8 = kc % 6;
        int ci = ci8 * 8 + j;
        float v = 0.f;
        if (tap < 9) v = w3[((co * 48 + ci) * 3 + tap / 3) * 3 + tap % 3];
        wp3s[t] = (half_t)v;
        return;
    }
    t -= 21504;
    if (t < 23040) {
        int tap = t / 2304, r = t % 2304;
        int ci8 = r / 384, r2 = r % 384;
        int mm = r2 / 24, r3 = r2 % 24;
        int nt = r3 / 8, j = r3 % 8;
        int co = nt * 16 + mm, ci = ci8 * 8 + j;
        float v = 0.f;
        if (tap < 9) v = w4[((co * 48 + ci) * 3 + tap / 3) * 3 + tap % 3];
        wp4[t] = (half_t)v;
    }
}

// ===========================================================================
// Fused conv1(3->48) + conv2(48->48) + bias/leaky + 2x2 maxpool.
// (R9/R11-proven kernel, unchanged.)
// ===========================================================================
__global__ __launch_bounds__(512, 4) void conv12_k(const float* __restrict__ x,
                                                   const half_t* __restrict__ wp1,
                                                   const float* __restrict__ b1,
                                                   const half_t* __restrict__ wp2,
                                                   const float* __restrict__ b2,
                                                   half_t* __restrict__ out)
{
    __shared__ alignas(16) half_t in_t[624 * 56];   // conv1 out [px=row*34+col][co56]
    __shared__ alignas(16) half_t xt[21][36][4];    // x patch, ci-minor (pad 4)
    __shared__ alignas(16) half_t w1t[1920];        // [co][40]

    const int tid = threadIdx.x;
    const int n = blockIdx.z;
    const int hblk = blockIdx.x * 16, wblk = blockIdx.y * 32;
    const int lane = tid & 63, hp = tid >> 6;       // 8 waves = h-pairs 0..7
    const int m = lane & 15, g = lane >> 4;

    {
        const uint4* s = (const uint4*)wp1;
        uint4* d = (uint4*)w1t;
        if (tid < 240) d[tid] = s[tid];
    }
    for (int c = tid; c < 2268; c += 512) {
        int ci = c / 756, rem = c % 756;
        int row = rem / 36, col = rem % 36;
        int gh = hblk - 2 + row, gw = wblk - 2 + col;
        float v = 0.f;
        if ((unsigned)gh < 256u && (unsigned)gw < 256u)
            v = x[((n * 3 + ci) * 256 + gh) * 256 + gw];
        xt[row][col][ci] = (half_t)v;
    }
    __syncthreads();

    // =================== conv1 phase ===================
    int xoff[8];
    #pragma unroll
    for (int j = 0; j < 8; ++j) {
        int k = g * 8 + j;
        int tap = k / 3, ci = k - 3 * tap;
        int dr = tap / 3, ds = tap - 3 * dr;
        xoff[j] = (k < 27) ? ((dr * 36 + ds) * 8 + ci * 2) : 0;   // k>=27: weight=0
    }
    f16x8 wf[3];
    float bb1[12];
    #pragma unroll
    for (int nt = 0; nt < 3; ++nt) {
        wf[nt] = *(const f16x8*)((const char*)w1t + (nt * 16 + m) * 80 + g * 16);
        float4 bv = *(const float4*)(b1 + nt * 16 + 4 * g);
        bb1[nt * 4 + 0] = bv.x; bb1[nt * 4 + 1] = bv.y;
        bb1[nt * 4 + 2] = bv.z; bb1[nt * 4 + 3] = bv.w;
    }
    const char* xtb = (const char*)&xt[0][0][0];
    for (int t = hp; t < 39; t += 8) {
        int px = t * 16 + m;
        int row = px / 34, col = px - row * 34;
        int pxb = (row * 36 + col) * 8;
        f16x8 pf;
        #pragma unroll
        for (int j = 0; j < 8; ++j)
            pf[j] = *(const half_t*)(xtb + pxb + xoff[j]);
        bool inb = ((unsigned)(hblk - 1 + row) < 256u) && ((unsigned)(wblk - 1 + col) < 256u);
        #pragma unroll
        for (int nt = 0; nt < 3; ++nt) {
            f32x4 d = {0.f, 0.f, 0.f, 0.f};
            d = __builtin_amdgcn_mfma_f32_16x16x32_f16(wf[nt], pf, d, 0, 0, 0);
            f16x4 o;
            #pragma unroll
            for (int j = 0; j < 4; ++j) {
                float v = d[j] + bb1[nt * 4 + j];
                v = v > 0.f ? v : LEAKY * v;
                o[j] = inb ? (half_t)v : (half_t)0.f;
            }
            *(f16x4*)(&in_t[px * 56 + nt * 16 + 4 * g]) = o;
        }
    }

    // =================== conv2 phase (depth-4 B pipeline) ===================
    const int hpar = m & 1, wloc = m >> 1;
    const int abase = hp * 7616;                    // 2*hp * 34 * 112
    const char* ib = (const char*)in_t;
    const char* bp = (const char*)wp2 + m * 48;

    f16x8 bf[4][3], af[4];

#define BLOAD(S) { \
    int kc = 4 * (S) + g; int tap = kc / 6, ci8 = kc - tap * 6; \
    int boff = tap * 4608 + ci8 * 768; \
    bf[(S) & 3][0] = *(const f16x8*)(bp + boff); \
    bf[(S) & 3][1] = *(const f16x8*)(bp + boff + 16); \
    bf[(S) & 3][2] = *(const f16x8*)(bp + boff + 32); }
#define ALOAD(S) { \
    int kc = 4 * (S) + g; int tap = kc / 6, ci8 = kc - tap * 6; \
    int dr = tap / 3, ds = tap - 3 * dr; \
    if (tap == 9) { dr = 0; ds = 0; } \
    int aoff = ((hpar + dr) * 34 + (wloc + ds)) * 112 + ci8 * 16 + abase; \
    af[0] = *(const f16x8*)(ib + aoff); \
    af[1] = *(const f16x8*)(ib + aoff + 896); \
    af[2] = *(const f16x8*)(ib + aoff + 1792); \
    af[3] = *(const f16x8*)(ib + aoff + 2688); }
#define MM(P) { \
    __builtin_amdgcn_s_setprio(1); \
    _Pragma("unroll") \
    for (int mt = 0; mt < 4; ++mt) { \
        acc[mt][0] = __builtin_amdgcn_mfma_f32_16x16x32_f16(af[mt], bf[P][0], acc[mt][0], 0, 0, 0); \
        acc[mt][1] = __builtin_amdgcn_mfma_f32_16x16x32_f16(af[mt], bf[P][1], acc[mt][1], 0, 0, 0); \
        acc[mt][2] = __builtin_amdgcn_mfma_f32_16x16x32_f16(af[mt], bf[P][2], acc[mt][2], 0, 0, 0); \
    } \
    __builtin_amdgcn_s_setprio(0); }

    BLOAD(0); BLOAD(1); BLOAD(2); BLOAD(3);
    __syncthreads();

    f32x4 acc[4][3];
    #pragma unroll
    for (int mt = 0; mt < 4; ++mt)
        #pragma unroll
        for (int nt = 0; nt < 3; ++nt)
            acc[mt][nt] = (f32x4){0.f, 0.f, 0.f, 0.f};

    #pragma unroll
    for (int s = 0; s < 14; ++s) {
        ALOAD(s);
        MM(s & 3);
        if (s < 10) BLOAD(s + 4);
    }
#undef BLOAD
#undef ALOAD
#undef MM

    int hq = blockIdx.x * 8 + hp;
    #pragma unroll
    for (int nt = 0; nt < 3; ++nt) {
        int co = nt * 16 + m;
        float bb = b2[co];
        #pragma unroll
        for (int mt = 0; mt < 4; ++mt) {
            float pmax = -1e30f;
            #pragma unroll
            for (int j = 0; j < 4; ++j) {
                float v = acc[mt][nt][j] + bb;
                v = v > 0.f ? v : LEAKY * v;
                pmax = fmaxf(pmax, v);
            }
            int wq = blockIdx.y * 16 + mt * 4 + g;
            out[((n * 128 + hq) * 128 + wq) * 48 + co] = (half_t)pmax;
        }
    }
}

// ===========================================================================
// Fused conv3(48->48 @128 + pool -> 64) + conv4(48->48 @64 + pool -> 32 fp32).
// R11's verified math; restructured for speed: 512 thr (8 waves, 2 blocks/CU
// = 16 waves/CU) and NO weight hoist (wf3 read per step from L1-hot global).
// conv3: swapped MFMA on 25 tiles of 4x4 px, <=4 tiles/wave; in-register
// 2x2 pool via shfl_xor(1)+shfl_xor(4); writers m in {0,2,8,10}.
// conv4: waves 0..3, MT=1, B from wp4 packed.
// ===========================================================================
__global__ __launch_bounds__(512, 2) void conv34_k(const half_t* __restrict__ act2,
                                                   const half_t* __restrict__ wp3s,
                                                   const float* __restrict__ b3,
                                                   const half_t* __restrict__ wp4,
                                                   const float* __restrict__ b4,
                                                   float* __restrict__ out)
{
    __shared__ alignas(16) half_t a2t[22 * 22 * 56];   // 54208 B act2 patch
    __shared__ alignas(16) half_t in_t[100 * 56];      // 11200 B pooled conv3

    const int tid = threadIdx.x;
    const int n = blockIdx.z;
    const int bx = blockIdx.x, by = blockIdx.y;
    const int lane = tid & 63, hp = tid >> 6;          // 8 waves
    const int m = lane & 15, g = lane >> 4;

    // ---- stage act2 rows bx*16-3..+18, cols by*16-3..+18 (22x22, zero-pad) ----
    {
        const uint4* s4 = (const uint4*)act2;
        uint4* d = (uint4*)a2t;
        #pragma unroll
        for (int i = 0; i < 7; ++i) {
            int c = tid + i * 512;
            if (c < 2904) {
                int row = c / 132, rem = c - row * 132;
                int col = rem / 6, sub = rem - col * 6;
                int gh = bx * 16 - 3 + row, gw = by * 16 - 3 + col;
                uint4 v = {0u, 0u, 0u, 0u};
                if ((unsigned)gh < 128u && (unsigned)gw < 128u)
                    v = s4[((n * 128 + gh) * 128 + gw) * 6 + sub];
                d[(row * 22 + col) * 7 + sub] = v;
            }
        }
    }

    // per-lane conv3 A/B addressing (no hoist)
    const char* w3p = (const char*)wp3s + m * 896;     // + nt*14336 + kc*16
    int aoff3[14];
    #pragma unroll
    for (int s = 0; s < 14; ++s) {
        int kc = 4 * s + g;
        int tap = kc / 6, ci8 = kc - tap * 6;
        int dr = tap / 3, ds = tap - 3 * dr;
        if (tap == 9) { dr = 0; ds = 0; }              // weights are zero there
        aoff3[s] = (dr * 22 + ds) * 112 + ci8 * 16;
    }
    float bb3[12];
    #pragma unroll
    for (int nt = 0; nt < 3; ++nt) {
        float4 bv = *(const float4*)(b3 + nt * 16 + 4 * g);
        bb3[nt * 4 + 0] = bv.x; bb3[nt * 4 + 1] = bv.y;
        bb3[nt * 4 + 2] = bv.z; bb3[nt * 4 + 3] = bv.w;
    }
    __syncthreads();

    // =================== conv3 + in-register 2x2 pool ===================
    const char* ab = (const char*)a2t;
    const int prow = m >> 2, pcol = m & 3;             // pixel within 4x4 tile
    for (int t = hp; t < 25; t += 8) {
        int tr = t / 5, tc = t - tr * 5;
        int rr = tr * 4 + prow, cc = tc * 4 + pcol;    // conv3 rel coords (0..19)
        int pxoff = (rr * 22 + cc) * 112;
        f32x4 d3[3];
        d3[0] = (f32x4){0.f, 0.f, 0.f, 0.f};
        d3[1] = (f32x4){0.f, 0.f, 0.f, 0.f};
        d3[2] = (f32x4){0.f, 0.f, 0.f, 0.f};
        #pragma unroll
        for (int s = 0; s < 14; ++s) {
            int kc16 = (4 * s + g) * 16;
            f16x8 pa = *(const f16x8*)(ab + pxoff + aoff3[s]);
            d3[0] = __builtin_amdgcn_mfma_f32_16x16x32_f16(*(const f16x8*)(w3p + kc16), pa, d3[0], 0, 0, 0);
            d3[1] = __builtin_amdgcn_mfma_f32_16x16x32_f16(*(const f16x8*)(w3p + kc16 + 14336), pa, d3[1], 0, 0, 0);
            d3[2] = __builtin_amdgcn_mfma_f32_16x16x32_f16(*(const f16x8*)(w3p + kc16 + 28672), pa, d3[2], 0, 0, 0);
        }
        int pp_r = tr * 2 + (m >> 3);                  // pooled rel row (0..9)
        int pp_c = tc * 2 + ((m & 2) >> 1);            // pooled rel col (0..9)
        bool valid = ((unsigned)(bx * 8 - 1 + pp_r) < 64u) &&
                     ((unsigned)(by * 8 - 1 + pp_c) < 64u);
        #pragma unroll
        for (int nt = 0; nt < 3; ++nt) {
            f16x4 o;
            #pragma unroll
            for (int j = 0; j < 4; ++j) {
                float v = d3[nt][j];
                v = fmaxf(v, __shfl_xor(v, 1));        // pool cols
                v = fmaxf(v, __shfl_xor(v, 4));        // pool rows
                float r = v + bb3[nt * 4 + j];
                r = r > 0.f ? r : LEAKY * r;
                o[j] = valid ? (half_t)r : (half_t)0.f;
            }
            if ((m & 5) == 0)                          // m in {0,2,8,10}
                *(f16x4*)(&in_t[(pp_r * 10 + pp_c) * 56 + nt * 16 + 4 * g]) = o;
        }
    }
    __syncthreads();

    // =================== conv4 phase (waves 0..3, MT=1) ===================
    if (hp < 4) {
        const int hpar = m & 1, wloc = m >> 1;
        const char* ib = (const char*)in_t;
        const char* bp = (const char*)wp4 + m * 48;
        const int abase = hp * 2240;                   // 2*hp * 10 * 112

        f32x4 acc[3];
        #pragma unroll
        for (int nt = 0; nt < 3; ++nt) acc[nt] = (f32x4){0.f, 0.f, 0.f, 0.f};

        #pragma unroll
        for (int s = 0; s < 14; ++s) {
            int kc = 4 * s + g;
            int tap = kc / 6, ci8 = kc - tap * 6;
            int dr = tap / 3, ds = tap - 3 * dr;
            if (tap == 9) { dr = 0; ds = 0; }
            int aoff = ((hpar + dr) * 10 + (wloc + ds)) * 112 + ci8 * 16 + abase;
            int boff = tap * 4608 + ci8 * 768;
            f16x8 a = *(const f16x8*)(ib + aoff);
            acc[0] = __builtin_amdgcn_mfma_f32_16x16x32_f16(a, *(const f16x8*)(bp + boff), acc[0], 0, 0, 0);
            acc[1] = __builtin_amdgcn_mfma_f32_16x16x32_f16(a, *(const f16x8*)(bp + boff + 16), acc[1], 0, 0, 0);
            acc[2] = __builtin_amdgcn_mfma_f32_16x16x32_f16(a, *(const f16x8*)(bp + boff + 32), acc[2], 0, 0, 0);
        }

        int hq = bx * 4 + hp;
        int wq = by * 4 + g;
        #pragma unroll
        for (int nt = 0; nt < 3; ++nt) {
            int co = nt * 16 + m;
            float bb = b4[co];
            float pmax = -1e30f;
            #pragma unroll
            for (int j = 0; j < 4; ++j) {
                float v = acc[nt][j] + bb;
                v = v > 0.f ? v : LEAKY * v;
                pmax = fmaxf(pmax, v);
            }
            out[(((long)n * 48 + co) * 32 + hq) * 32 + wq] = pmax;
        }
    }
}

// ===========================================================================
extern "C" void kernel_launch(void* const* d_in, const int* in_sizes, int n_in,
                              void* d_out, int out_size, void* d_ws, size_t ws_size,
                              hipStream_t stream)
{
    const float* x  = (const float*)d_in[0];
    const float* w1 = (const float*)d_in[1];
    const float* b1 = (const float*)d_in[2];
    const float* w2 = (const float*)d_in[3];
    const float* b2 = (const float*)d_in[4];
    const float* w3 = (const float*)d_in[5];
    const float* b3 = (const float*)d_in[6];
    const float* w4 = (const float*)d_in[7];
    const float* b4 = (const float*)d_in[8];

    half_t* Wb = (half_t*)d_ws;
    half_t* wp1  = Wb;                      // 1920 (pad 2048)
    half_t* wp2  = Wb + 2048;               // 23040
    half_t* wp3s = wp2 + 23040;             // 21504
    half_t* wp4  = wp3s + 21504;            // 23040
    half_t* act2 = wp4 + 23040;             // 8*128*128*48 = 6291456

    prep_w_k<<<dim3(136), 512, 0, stream>>>(w1, w2, w3, w4, wp1, wp2, wp3s, wp4);

    // fused conv1+conv2: 3->48->48 @256 + pool -> act2 (128x128 NHWC-48)
    conv12_k<<<dim3(16, 8, 8), 512, 0, stream>>>(x, wp1, b1, wp2, b2, act2);
    // fused conv3+conv4: -> fp32 NCHW 32x32
    conv34_k<<<dim3(8, 8, 8), 512, 0, stream>>>(act2, wp3s, b3, wp4, b4, (float*)d_out);
}

// Round 16
// 58.238 us; speedup vs baseline: 1.2889x; 1.2889x over previous
//
#include <hip/hip_runtime.h>
#include <hip/hip_bf16.h>

typedef _Float16 half_t;
typedef _Float16 f16x8 __attribute__((ext_vector_type(8)));
typedef _Float16 f16x4 __attribute__((ext_vector_type(4)));
typedef float f32x4 __attribute__((ext_vector_type(4)));

#define LEAKY 0.1f

// ===========================================================================
// prep: wp1 = [co(48)][40] (k = tap*3+ci, 27..39 = 0)
//       wp2 = [tap(10)][ci8(6)][m(16)][nt(3)][j(8)] halfs, tap 9 = zeros.
// ===========================================================================
__global__ __launch_bounds__(512) void prep_w_k(const float* __restrict__ w1,
                                                const float* __restrict__ w2,
                                                half_t* __restrict__ wp1,
                                                half_t* __restrict__ wp2)
{
    int t = blockIdx.x * 512 + threadIdx.x;
    if (t < 1920) {
        int co = t / 40, kk = t % 40;
        float v = 0.f;
        if (kk < 27) {
            int tap = kk / 3, ci = kk % 3;
            v = w1[((co * 3 + ci) * 3 + tap / 3) * 3 + tap % 3];
        }
        wp1[t] = (half_t)v;
        return;
    }
    int t2 = t - 1920;
    if (t2 >= 23040) return;
    int tap = t2 / 2304, r = t2 % 2304;
    int ci8 = r / 384, r2 = r % 384;
    int mm = r2 / 24, r3 = r2 % 24;
    int nt = r3 / 8, j = r3 % 8;
    int co = nt * 16 + mm, ci = ci8 * 8 + j;
    float v = 0.f;
    if (tap < 9) v = w2[((co * 48 + ci) * 3 + tap / 3) * 3 + tap % 3];
    wp2[t2] = (half_t)v;
}

// ===========================================================================
// Fused conv1(3->48) + conv2(48->48) + bias/leaky + 2x2 maxpool.
// Block: 512 thr = 8 waves; conv2-input tile 16 rows x 32 cols -> pooled 8x16.
// conv1: swapped-operand MFMA -> ds_write_b64 into conv2's A layout.
// conv2: K=(tap,ci) 432 pad 448, 14 steps; B from global L2 with a DEPTH-4
// software pipeline (prologue issued before the barrier).
// Blocks 0..89 also emit wp34 for conv3/conv4.
// ===========================================================================
__global__ __launch_bounds__(512, 4) void conv12_k(const float* __restrict__ x,
                                                   const half_t* __restrict__ wp1,
                                                   const float* __restrict__ b1,
                                                   const half_t* __restrict__ wp2,
                                                   const float* __restrict__ b2,
                                                   const float* __restrict__ w3,
                                                   const float* __restrict__ w4,
                                                   half_t* __restrict__ wp34,
                                                   half_t* __restrict__ out)
{
    __shared__ alignas(16) half_t in_t[624 * 56];   // conv1 out [px=row*34+col][co56]
    __shared__ alignas(16) half_t xt[21][36][4];    // x patch, ci-minor (pad 4)
    __shared__ alignas(16) half_t w1t[1920];        // [co][40]

    const int tid = threadIdx.x;
    const int n = blockIdx.z;
    const int hblk = blockIdx.x * 16, wblk = blockIdx.y * 32;
    const int lane = tid & 63, hp = tid >> 6;       // 8 waves = h-pairs 0..7
    const int m = lane & 15, g = lane >> 4;

    // ---- folded wp3/wp4 prep (blocks 0..89) ----
    {
        int bid = blockIdx.x + 16 * (blockIdx.y + 8 * blockIdx.z);
        int t2 = bid * 512 + tid;
        if (t2 < 46080) {
            int layer = t2 / 23040, r0 = t2 % 23040;
            int tap = r0 / 2304, r = r0 % 2304;
            int ci8 = r / 384, r2 = r % 384;
            int mm = r2 / 24, r3 = r2 % 24;
            int nt = r3 / 8, j = r3 % 8;
            int co = nt * 16 + mm, ci = ci8 * 8 + j;
            const float* src = layer ? w4 : w3;
            float v = 0.f;
            if (tap < 9) v = src[((co * 48 + ci) * 3 + tap / 3) * 3 + tap % 3];
            wp34[t2] = (half_t)v;
        }
    }
    // ---- w1t: linear copy 240 uint4 ----
    {
        const uint4* s = (const uint4*)wp1;
        uint4* d = (uint4*)w1t;
        if (tid < 240) d[tid] = s[tid];
    }
    // ---- xt: rows hblk-2..hblk+18 (21), cols wblk-2..wblk+33 (36) ----
    for (int c = tid; c < 2268; c += 512) {
        int ci = c / 756, rem = c % 756;
        int row = rem / 36, col = rem % 36;
        int gh = hblk - 2 + row, gw = wblk - 2 + col;
        float v = 0.f;
        if ((unsigned)gh < 256u && (unsigned)gw < 256u)
            v = x[((n * 3 + ci) * 256 + gh) * 256 + gw];
        xt[row][col][ci] = (half_t)v;
    }
    __syncthreads();

    // =================== conv1 phase ===================
    int xoff[8];
    #pragma unroll
    for (int j = 0; j < 8; ++j) {
        int k = g * 8 + j;
        int tap = k / 3, ci = k - 3 * tap;
        int dr = tap / 3, ds = tap - 3 * dr;
        xoff[j] = (k < 27) ? ((dr * 36 + ds) * 8 + ci * 2) : 0;   // k>=27: weight=0
    }
    f16x8 wf[3];
    float bb1[12];
    #pragma unroll
    for (int nt = 0; nt < 3; ++nt) {
        wf[nt] = *(const f16x8*)((const char*)w1t + (nt * 16 + m) * 80 + g * 16);
        float4 bv = *(const float4*)(b1 + nt * 16 + 4 * g);
        bb1[nt * 4 + 0] = bv.x; bb1[nt * 4 + 1] = bv.y;
        bb1[nt * 4 + 2] = bv.z; bb1[nt * 4 + 3] = bv.w;
    }
    const char* xtb = (const char*)&xt[0][0][0];
    for (int t = hp; t < 39; t += 8) {
        int px = t * 16 + m;
        int row = px / 34, col = px - row * 34;
        int pxb = (row * 36 + col) * 8;
        f16x8 pf;
        #pragma unroll
        for (int j = 0; j < 8; ++j)
            pf[j] = *(const half_t*)(xtb + pxb + xoff[j]);
        bool inb = ((unsigned)(hblk - 1 + row) < 256u) && ((unsigned)(wblk - 1 + col) < 256u);
        #pragma unroll
        for (int nt = 0; nt < 3; ++nt) {
            f32x4 d = {0.f, 0.f, 0.f, 0.f};
            d = __builtin_amdgcn_mfma_f32_16x16x32_f16(wf[nt], pf, d, 0, 0, 0);
            f16x4 o;
            #pragma unroll
            for (int j = 0; j < 4; ++j) {
                float v = d[j] + bb1[nt * 4 + j];
                v = v > 0.f ? v : LEAKY * v;
                o[j] = inb ? (half_t)v : (half_t)0.f;
            }
            *(f16x4*)(&in_t[px * 56 + nt * 16 + 4 * g]) = o;
        }
    }

    // =================== conv2 phase (depth-4 B pipeline) ===================
    const int hpar = m & 1, wloc = m >> 1;
    const int abase = hp * 7616;                    // 2*hp * 34 * 112
    const char* ib = (const char*)in_t;
    const char* bp = (const char*)wp2 + m * 48;

    f16x8 bf[4][3], af[4];

#define BLOAD(S) { \
    int kc = 4 * (S) + g; int tap = kc / 6, ci8 = kc - tap * 6; \
    int boff = tap * 4608 + ci8 * 768; \
    bf[(S) & 3][0] = *(const f16x8*)(bp + boff); \
    bf[(S) & 3][1] = *(const f16x8*)(bp + boff + 16); \
    bf[(S) & 3][2] = *(const f16x8*)(bp + boff + 32); }
#define ALOAD(S) { \
    int kc = 4 * (S) + g; int tap = kc / 6, ci8 = kc - tap * 6; \
    int dr = tap / 3, ds = tap - 3 * dr; \
    if (tap == 9) { dr = 0; ds = 0; } \
    int aoff = ((hpar + dr) * 34 + (wloc + ds)) * 112 + ci8 * 16 + abase; \
    af[0] = *(const f16x8*)(ib + aoff); \
    af[1] = *(const f16x8*)(ib + aoff + 896); \
    af[2] = *(const f16x8*)(ib + aoff + 1792); \
    af[3] = *(const f16x8*)(ib + aoff + 2688); }
#define MM(P) { \
    __builtin_amdgcn_s_setprio(1); \
    _Pragma("unroll") \
    for (int mt = 0; mt < 4; ++mt) { \
        acc[mt][0] = __builtin_amdgcn_mfma_f32_16x16x32_f16(af[mt], bf[P][0], acc[mt][0], 0, 0, 0); \
        acc[mt][1] = __builtin_amdgcn_mfma_f32_16x16x32_f16(af[mt], bf[P][1], acc[mt][1], 0, 0, 0); \
        acc[mt][2] = __builtin_amdgcn_mfma_f32_16x16x32_f16(af[mt], bf[P][2], acc[mt][2], 0, 0, 0); \
    } \
    __builtin_amdgcn_s_setprio(0); }

    // prologue: B for steps 0..3 in flight across the barrier
    BLOAD(0); BLOAD(1); BLOAD(2); BLOAD(3);
    __syncthreads();

    f32x4 acc[4][3];
    #pragma unroll
    for (int mt = 0; mt < 4; ++mt)
        #pragma unroll
        for (int nt = 0; nt < 3; ++nt)
            acc[mt][nt] = (f32x4){0.f, 0.f, 0.f, 0.f};

    #pragma unroll
    for (int s = 0; s < 14; ++s) {
        ALOAD(s);
        MM(s & 3);
        if (s < 10) BLOAD(s + 4);
    }
#undef BLOAD
#undef ALOAD
#undef MM

    // ---- epilogue: bias + leaky + 2x2 maxpool -> act2 NHWC-48 ----
    int hq = blockIdx.x * 8 + hp;
    #pragma unroll
    for (int nt = 0; nt < 3; ++nt) {
        int co = nt * 16 + m;
        float bb = b2[co];
        #pragma unroll
        for (int mt = 0; mt < 4; ++mt) {
            float pmax = -1e30f;
            #pragma unroll
            for (int j = 0; j < 4; ++j) {
                float v = acc[mt][nt][j] + bb;
                v = v > 0.f ? v : LEAKY * v;
                pmax = fmaxf(pmax, v);
            }
            int wq = blockIdx.y * 16 + mt * 4 + g;
            out[((n * 128 + hq) * 128 + wq) * 48 + co] = (half_t)pmax;
        }
    }
}

// ===========================================================================
// convpool (48->48, 3x3 pad1 + bias + leaky + 2x2 maxpool), depth-4 B pipe.
// Block: 256 thr = 4 waves; wave = 1 h-pair x (8*MT) cols. A: LDS; B: global.
// NTS = couts/16 per block; grid z = ntb*8 + n.
// ===========================================================================
template<int H, int W, int MT, int NTS, bool FINAL>
__global__ __launch_bounds__(256, 4)
void convpool4_k(const half_t* __restrict__ in,
                 const half_t* __restrict__ wp,
                 const float* __restrict__ bias,
                 void* __restrict__ outv)
{
    constexpr int HO = H / 2, WO = W / 2;
    constexpr int TC = 8 * MT + 2;
    constexpr int NU4 = 10 * TC * 6;

    __shared__ alignas(16) half_t in_t[10][TC][56];

    int tid = threadIdx.x;
    int n = blockIdx.z & 7, ntb = blockIdx.z >> 3;
    int hblk = blockIdx.x * 8, wblk = blockIdx.y * (8 * MT);
    int lane = tid & 63, hp = tid >> 6;
    int m = lane & 15, g = lane >> 4;
    int hpar = m & 1, wloc = m >> 1;

    {
        const uint4* s4 = (const uint4*)in;
        uint4* d = (uint4*)&in_t[0][0][0];
        #pragma unroll
        for (int i = 0; i < (NU4 + 255) / 256; ++i) {
            int c = tid + i * 256;
            if (c < NU4) {
                int row = c / (TC * 6);
                int rem = c - row * (TC * 6);
                int pix = rem / 6;
                int sub = rem - pix * 6;
                int gh = hblk - 1 + row, gw = wblk - 1 + pix;
                uint4 v = {0u, 0u, 0u, 0u};
                if ((unsigned)gh < (unsigned)H && (unsigned)gw < (unsigned)W)
                    v = s4[((n * H + gh) * W + gw) * 6 + sub];
                d[(row * TC + pix) * 7 + sub] = v;
            }
        }
    }

    int abase = hp * 2 * TC * 112;
    const char* ib = (const char*)&in_t[0][0][0];
    const char* bp = (const char*)wp + m * 48 + ntb * NTS * 16;

    f16x8 bf[4][NTS], a[MT];

#define BLOAD(S) { \
    int kc = 4 * (S) + g; int tap = kc / 6, ci8 = kc - tap * 6; \
    int boff = tap * 4608 + ci8 * 768; \
    _Pragma("unroll") \
    for (int nt = 0; nt < NTS; ++nt) \
        bf[(S) & 3][nt] = *(const f16x8*)(bp + boff + nt * 16); }

    BLOAD(0); BLOAD(1); BLOAD(2); BLOAD(3);

    f32x4 acc[MT][NTS];
    #pragma unroll
    for (int mt = 0; mt < MT; ++mt)
        #pragma unroll
        for (int nt = 0; nt < NTS; ++nt)
            acc[mt][nt] = (f32x4){0.f, 0.f, 0.f, 0.f};

    __syncthreads();

    #pragma unroll
    for (int s = 0; s < 14; ++s) {
        int kc = 4 * s + g;
        int tap = kc / 6, ci8 = kc - tap * 6;
        int dr = tap / 3, ds = tap - 3 * dr;
        if (tap == 9) { dr = 0; ds = 0; }
        int aoff = ((hpar + dr) * TC + (wloc + ds)) * 112 + ci8 * 16;
        #pragma unroll
        for (int mt = 0; mt < MT; ++mt)
            a[mt] = *(const f16x8*)(ib + abase + aoff + mt * 896);
        __builtin_amdgcn_s_setprio(1);
        #pragma unroll
        for (int mt = 0; mt < MT; ++mt)
            #pragma unroll
            for (int nt = 0; nt < NTS; ++nt)
                acc[mt][nt] = __builtin_amdgcn_mfma_f32_16x16x32_f16(a[mt], bf[s & 3][nt], acc[mt][nt], 0, 0, 0);
        __builtin_amdgcn_s_setprio(0);
        if (s < 10) BLOAD(s + 4);
    }
#undef BLOAD

    int hq = blockIdx.x * 4 + hp;
    #pragma unroll
    for (int nt = 0; nt < NTS; ++nt) {
        int co = (ntb * NTS + nt) * 16 + m;
        float bb = bias[co];
        #pragma unroll
        for (int mt = 0; mt < MT; ++mt) {
            float pmax = -1e30f;
            #pragma unroll
            for (int j = 0; j < 4; ++j) {
                float v = acc[mt][nt][j] + bb;
                v = v > 0.f ? v : LEAKY * v;
                pmax = fmaxf(pmax, v);
            }
            int wq = blockIdx.y * (4 * MT) + mt * 4 + g;
            if (FINAL)
                ((float*)outv)[(((long)n * 48 + co) * HO + hq) * WO + wq] = pmax;
            else
                ((half_t*)outv)[((n * HO + hq) * WO + wq) * 48 + co] = (half_t)pmax;
        }
    }
}

// ===========================================================================
extern "C" void kernel_launch(void* const* d_in, const int* in_sizes, int n_in,
                              void* d_out, int out_size, void* d_ws, size_t ws_size,
                              hipStream_t stream)
{
    const float* x  = (const float*)d_in[0];
    const float* w1 = (const float*)d_in[1];
    const float* b1 = (const float*)d_in[2];
    const float* w2 = (const float*)d_in[3];
    const float* b2 = (const float*)d_in[4];
    const float* w3 = (const float*)d_in[5];
    const float* b3 = (const float*)d_in[6];
    const float* w4 = (const float*)d_in[7];
    const float* b4 = (const float*)d_in[8];

    half_t* Wb = (half_t*)d_ws;
    half_t* wp1  = Wb;                      // 1920 (pad 2048)
    half_t* wp2  = Wb + 2048;               // 23040
    half_t* wp34 = wp2 + 23040;             // 2 x 23040
    half_t* act2 = wp34 + 46080;            // 8*128*128*48 = 6291456
    half_t* act3 = act2 + 6291456;          // 8*64*64*48   = 1572864

    prep_w_k<<<dim3(49), 512, 0, stream>>>(w1, w2, wp1, wp2);

    // fused conv1+conv2: 3->48->48 @256 + pool -> act2 (128x128 NHWC-48)
    conv12_k<<<dim3(16, 8, 8), 512, 0, stream>>>(x, wp1, b1, wp2, b2, w3, w4, wp34, act2);
    // conv3: 48->48 @128 + pool -> 64
    convpool4_k<128, 128, 4, 3, false><<<dim3(16, 4, 8), 256, 0, stream>>>(act2, wp34, b3, act3);
    // conv4: 48->48 @64 + pool -> 32, fp32 NCHW out; cout split 3-ways
    convpool4_k<64, 64, 2, 1, true><<<dim3(8, 4, 24), 256, 0, stream>>>(act3, wp34 + 23040, b4, d_out);
}